// Round 3
// baseline (236.389 us; speedup 1.0000x reference)
//
#include <hip/hip_runtime.h>
#include <hip/hip_bf16.h>
#include <stdint.h>

#define DI __device__ __forceinline__

typedef __attribute__((ext_vector_type(8))) short short8;
typedef __attribute__((ext_vector_type(4))) short short4v;
typedef __attribute__((ext_vector_type(4))) float f32x4;

static constexpr int TT = 4096;   // seq len
static constexpr int CC = 1024;   // n_embed
static constexpr int HH = 64;     // head size

DI short f2b(float x) {
  __hip_bfloat16 h = __float2bfloat16(x);
  return __builtin_bit_cast(short, h);
}

DI f32x4 MFMA(short8 a, short8 b, f32x4 c) {
  return __builtin_amdgcn_mfma_f32_16x16x32_bf16(a, b, c, 0, 0, 0);
}

// Pin a loaded fragment live at this point (stop the compiler sinking the load)
#define KEEP8(x) asm volatile("" :: "v"(x))

// ---------------------------------------------------------------------------
// Kernel 0: transpose weights W[k][n] f32 -> Wt[mat][n][k] bf16  (3*64*1024)
// ---------------------------------------------------------------------------
__global__ __launch_bounds__(256) void prep_wt(const float* __restrict__ Wq,
                                               const float* __restrict__ Wk,
                                               const float* __restrict__ Wv,
                                               short* __restrict__ Wt) {
  int o = blockIdx.x * 256 + threadIdx.x;       // < 196608
  int mat = o >> 16;
  int rem = o & 65535;
  int n = rem >> 10;
  int k = rem & 1023;
  const float* W = (mat == 0) ? Wq : ((mat == 1) ? Wk : Wv);
  Wt[o] = f2b(W[k * HH + n]);
}

// ---------------------------------------------------------------------------
// Kernel 1: fused QKV projection, barrier-free K-split.
// Block = 32-row strip; wave w handles K in [256w, 256w+256). No LDS in the
// main loop: A-frags direct from x (HBM stream, read exactly once), B-frags
// direct from L2-resident Wt. 2-buffer LDS tree merge + coalesced epilogue.
// ---------------------------------------------------------------------------
__global__ __launch_bounds__(256, 2) void qkv_gemm(const float* __restrict__ x,
                                                   const short* __restrict__ Wt,
                                                   const float* __restrict__ bq,
                                                   const float* __restrict__ bk,
                                                   const float* __restrict__ bv,
                                                   short* __restrict__ qbuf,
                                                   short* __restrict__ kbuf,
                                                   short* __restrict__ vT) {
  __shared__ float lds_acc[2][32 * 196];   // stride 196: 2-way banks (free)

  const int tid = threadIdx.x;
  const int w = tid >> 6, lane = tid & 63;
  const int c = lane & 15, g = lane >> 4;
  const int m0 = blockIdx.x * 32;
  const int kb0 = w * 256;

  f32x4 acc[2][12] = {};   // [mf][nf] : 32 rows x 192 cols

#pragma unroll
  for (int s8 = 0; s8 < 8; ++s8) {
    const int k0 = kb0 + s8 * 32;
    // A fragments straight from x (8 f32 -> 8 bf16 per lane per mf)
    short8 afr[2];
#pragma unroll
    for (int mf = 0; mf < 2; ++mf) {
      const float* ap = x + (size_t)(m0 + 16 * mf + c) * CC + k0 + 8 * g;
      float4 a0 = ((const float4*)ap)[0];
      float4 a1 = ((const float4*)ap)[1];
      short8 p;
      p[0] = f2b(a0.x); p[1] = f2b(a0.y); p[2] = f2b(a0.z); p[3] = f2b(a0.w);
      p[4] = f2b(a1.x); p[5] = f2b(a1.y); p[6] = f2b(a1.z); p[7] = f2b(a1.w);
      afr[mf] = p;
    }
    // B fragments from Wt (L2-hot), 12 nf covering 192 cols
#pragma unroll
    for (int nf = 0; nf < 12; ++nf) {
      const int mat = nf >> 2;
      const int nn = (nf & 3) * 16 + c;
      short8 bfr = *(const short8*)(Wt + mat * 65536 + nn * CC + k0 + 8 * g);
      acc[0][nf] = MFMA(afr[0], bfr, acc[0][nf]);
      acc[1][nf] = MFMA(afr[1], bfr, acc[1][nf]);
    }
  }

  // ---- tree merge: w2->bufA, w3->bufB; then w0 += bufA, w1 += bufB
  float* bufA = lds_acc[0];
  float* bufB = lds_acc[1];
  if (w >= 2) {
    float* buf = (w == 2) ? bufA : bufB;
#pragma unroll
    for (int mf = 0; mf < 2; ++mf)
#pragma unroll
      for (int nf = 0; nf < 12; ++nf)
#pragma unroll
        for (int r = 0; r < 4; ++r)
          buf[(16 * mf + 4 * g + r) * 196 + 16 * nf + c] = acc[mf][nf][r];
  }
  __syncthreads();
  if (w < 2) {
    float* buf = (w == 0) ? bufA : bufB;
#pragma unroll
    for (int mf = 0; mf < 2; ++mf)
#pragma unroll
      for (int nf = 0; nf < 12; ++nf)
#pragma unroll
        for (int r = 0; r < 4; ++r)
          buf[(16 * mf + 4 * g + r) * 196 + 16 * nf + c] += acc[mf][nf][r];
  }
  __syncthreads();

  // ---- epilogue: wave w owns mat w (cols 64w..64w+63); wave 3 idle.
  const float QSCALE = 0.125f * 1.44269504088896340736f;  // 1/sqrt(64)*log2(e)
  const int bb = m0 >> 12;
  const int t0 = m0 & 4095;
  if (w < 3) {
    const int n = lane;                    // 0..63
    const int cg = w * 64 + n;
    const float* bp = (w == 0) ? bq : ((w == 1) ? bk : bv);
    const float bias = bp[n];
    const float scale = (w == 0) ? QSCALE : 1.0f;
    if (w < 2) {
      short* op = (w == 0) ? qbuf : kbuf;
#pragma unroll
      for (int row = 0; row < 32; ++row) {
        float v = bufA[row * 196 + cg] + bufB[row * 196 + cg];
        op[(size_t)(m0 + row) * HH + n] = f2b((v + bias) * scale);
      }
    } else {
      // V: write transposed, 4 t-values packed per store
#pragma unroll
      for (int r4 = 0; r4 < 8; ++r4) {
        short4v pv;
#pragma unroll
        for (int j = 0; j < 4; ++j) {
          int row = 4 * r4 + j;
          float v = bufA[row * 196 + cg] + bufB[row * 196 + cg];
          pv[j] = f2b(v + bias);
        }
        *(short4v*)(vT + (size_t)(bb * HH + n) * TT + t0 + 4 * r4) = pv;
      }
    }
  }
}

// ---------------------------------------------------------------------------
// Kernel 2: causal flash attention, 4-way split-KV, wave-independent loop.
// 1024 blocks; block = one 16-row q-job, 4 waves = 4 KV quarters.
// XCD-aware: batch bb pinned to XCD pair (id&7)>>1 so its K/V stays L2-local.
// K(t+1) prefetched into registers (pinned); V issued early (pinned).
// ---------------------------------------------------------------------------
__global__ __launch_bounds__(256, 4) void attn(const short* __restrict__ qbuf,
                                               const short* __restrict__ kbuf,
                                               const short* __restrict__ vT,
                                               float* __restrict__ out) {
  __shared__ short lds_p[4 * 16 * 72];      // per-wave P scratch
  __shared__ float lds_o[3 * 16 * 66];      // merge O from waves 1..3
  __shared__ float lds_ml[3 * 2 * 16];      // merge m,l

  const int id = blockIdx.x;                 // 0..1023
  const int xcd = id & 7;
  const int bb = xcd >> 1;                   // batch on fixed XCD pair
  const int jidx = (id >> 3) * 2 + (xcd & 1);
  const int jj = 255 - jidx;                 // heavy jobs dispatched first
  const int tid = threadIdx.x;
  const int w = tid >> 6, lane = tid & 63;
  const int c = lane & 15, g = lane >> 4;

  const int q0 = jj * 16;
  const int nT = (jj >> 2) + 1;
  const int tlo = (w * nT) >> 2;
  const int thi = ((w + 1) * nT) >> 2;

  const short* qrow = qbuf + (size_t)(bb * TT + q0 + c) * HH;
  const short8 qfr0 = *(const short8*)(qrow + g * 8);
  const short8 qfr1 = *(const short8*)(qrow + 32 + g * 8);

  const short* kbase = kbuf + (size_t)bb * TT * HH;
  const short* vbase = vT + (size_t)bb * HH * TT;

  f32x4 acc[4] = {};
  float mreg[4], lreg[4];
#pragma unroll
  for (int r = 0; r < 4; ++r) { mreg[r] = -INFINITY; lreg[r] = 0.f; }

  short* pw = lds_p + w * 1152;
  const char* pb = (const char*)pw;

  short8 kc[4][2];
  if (tlo < thi) {
    const int kv0 = tlo * 64;
#pragma unroll
    for (int nf = 0; nf < 4; ++nf)
#pragma unroll
      for (int ks = 0; ks < 2; ++ks)
        kc[nf][ks] = *(const short8*)(kbase + (size_t)(kv0 + 16 * nf + c) * HH +
                                      ks * 32 + g * 8);
  }

  for (int t = tlo; t < thi; ++t) {
    const int kv0 = t * 64;
    // ---- S^ = Q K^T (exp2 domain; scale folded into q at projection)
    f32x4 sc[4] = {};
#pragma unroll
    for (int nf = 0; nf < 4; ++nf) {
      sc[nf] = MFMA(qfr0, kc[nf][0], sc[nf]);
      sc[nf] = MFMA(qfr1, kc[nf][1], sc[nf]);
    }
    // ---- prefetch next K tile into registers (pinned live here)
    short8 kn[4][2];
    if (t + 1 < thi) {
#pragma unroll
      for (int nf = 0; nf < 4; ++nf)
#pragma unroll
        for (int ks = 0; ks < 2; ++ks) {
          kn[nf][ks] = *(const short8*)(kbase +
                                        (size_t)(kv0 + 64 + 16 * nf + c) * HH +
                                        ks * 32 + g * 8);
          KEEP8(kn[nf][ks]);
        }
    }
    // ---- V fragments: issue now, consumed after softmax (~latency hidden)
    short8 vf[4][2];
#pragma unroll
    for (int hf = 0; hf < 4; ++hf) {
#pragma unroll
      for (int ks = 0; ks < 2; ++ks)
        vf[hf][ks] = *(const short8*)(vbase + (size_t)(16 * hf + c) * TT + kv0 +
                                      ks * 32 + g * 8);
      KEEP8(vf[hf][0]);
    }

    // ---- causal mask (diagonal tile only)
    if (t == nT - 1) {
#pragma unroll
      for (int nf = 0; nf < 4; ++nf)
#pragma unroll
        for (int r = 0; r < 4; ++r)
          if (kv0 + 16 * nf + c > q0 + 4 * g + r) sc[nf][r] = -INFINITY;
    }

    // ---- online softmax (row = 4g+r, reduce over 16 c-lanes)
    float mn[4], al[4], rs[4];
#pragma unroll
    for (int r = 0; r < 4; ++r) {
      float v = fmaxf(fmaxf(sc[0][r], sc[1][r]), fmaxf(sc[2][r], sc[3][r]));
      v = fmaxf(v, __shfl_xor(v, 1));
      v = fmaxf(v, __shfl_xor(v, 2));
      v = fmaxf(v, __shfl_xor(v, 4));
      v = fmaxf(v, __shfl_xor(v, 8));
      mn[r] = fmaxf(mreg[r], v);
      al[r] = exp2f(mreg[r] - mn[r]);
      rs[r] = 0.f;
    }
#pragma unroll
    for (int nf = 0; nf < 4; ++nf)
#pragma unroll
      for (int r = 0; r < 4; ++r) {
        float p = exp2f(sc[nf][r] - mn[r]);
        rs[r] += p;
        pw[(4 * g + r) * 72 + 16 * nf + c] = f2b(p);
      }
#pragma unroll
    for (int r = 0; r < 4; ++r) {
      float v = rs[r];
      v += __shfl_xor(v, 1);
      v += __shfl_xor(v, 2);
      v += __shfl_xor(v, 4);
      v += __shfl_xor(v, 8);
      lreg[r] = al[r] * lreg[r] + v;
      mreg[r] = mn[r];
    }
#pragma unroll
    for (int hf = 0; hf < 4; ++hf)
#pragma unroll
      for (int r = 0; r < 4; ++r) acc[hf][r] *= al[r];

    // ---- O += P V
#pragma unroll
    for (int ks = 0; ks < 2; ++ks) {
      short8 pa = *(const short8*)(pb + c * 144 + ks * 64 + g * 16);
#pragma unroll
      for (int hf = 0; hf < 4; ++hf)
        acc[hf] = MFMA(pa, vf[hf][ks], acc[hf]);
    }
    // ---- rotate prefetched K
#pragma unroll
    for (int nf = 0; nf < 4; ++nf) {
      kc[nf][0] = kn[nf][0];
      kc[nf][1] = kn[nf][1];
    }
  }

  // ---- 4-way merge: waves 1..3 dump, wave 0 combines + stores
  __syncthreads();
  if (w > 0) {
    float* od = lds_o + (w - 1) * (16 * 66);
#pragma unroll
    for (int hf = 0; hf < 4; ++hf)
#pragma unroll
      for (int r = 0; r < 4; ++r)
        od[(4 * g + r) * 66 + 16 * hf + c] = acc[hf][r];
    if (c == 0) {
      float* ml = lds_ml + (w - 1) * 32;
#pragma unroll
      for (int r = 0; r < 4; ++r) {
        ml[4 * g + r] = mreg[r];
        ml[16 + 4 * g + r] = lreg[r];
      }
    }
  }
  __syncthreads();
  if (w == 0) {
#pragma unroll
    for (int r = 0; r < 4; ++r) {
      float m = mreg[r];
      float ms[3], ls[3];
#pragma unroll
      for (int s = 0; s < 3; ++s) {
        ms[s] = lds_ml[s * 32 + 4 * g + r];
        ls[s] = lds_ml[s * 32 + 16 + 4 * g + r];
        m = fmaxf(m, ms[s]);
      }
      float a0 = exp2f(mreg[r] - m);
      float denom = a0 * lreg[r];
      float as[3];
#pragma unroll
      for (int s = 0; s < 3; ++s) {
        as[s] = exp2f(ms[s] - m);
        denom += as[s] * ls[s];
      }
      float inv = 1.0f / denom;
      float* orow = out + (size_t)(bb * TT + q0 + 4 * g + r) * HH;
#pragma unroll
      for (int hf = 0; hf < 4; ++hf) {
        float v = a0 * acc[hf][r];
#pragma unroll
        for (int s = 0; s < 3; ++s)
          v += as[s] * lds_o[s * (16 * 66) + (4 * g + r) * 66 + 16 * hf + c];
        orow[16 * hf + c] = v * inv;
      }
    }
  }
}

// ---------------------------------------------------------------------------
extern "C" void kernel_launch(void* const* d_in, const int* in_sizes, int n_in,
                              void* d_out, int out_size, void* d_ws, size_t ws_size,
                              hipStream_t stream) {
  const float* x  = (const float*)d_in[0];
  const float* Wq = (const float*)d_in[1];
  const float* bq = (const float*)d_in[2];
  const float* Wk = (const float*)d_in[3];
  const float* bk = (const float*)d_in[4];
  const float* Wv = (const float*)d_in[5];
  const float* bv = (const float*)d_in[6];
  float* out = (float*)d_out;

  char* ws = (char*)d_ws;
  short* Wt = (short*)ws;                           // 3*64*1024 bf16 = 384 KB
  short* qb = (short*)(ws + 393216);                // 16384*64 bf16 = 2 MB
  short* kb = qb + 16384 * 64;
  short* vT = kb + 16384 * 64;                      // total ~6.7 MB

  prep_wt<<<dim3(768), dim3(256), 0, stream>>>(Wq, Wk, Wv, Wt);
  qkv_gemm<<<dim3(512), dim3(256), 0, stream>>>(x, Wt, bq, bk, bv, qb, kb, vT);
  attn<<<dim3(1024), dim3(256), 0, stream>>>(qb, kb, vT, out);
}

// Round 6
// 194.559 us; speedup vs baseline: 1.2150x; 1.2150x over previous
//
#include <hip/hip_runtime.h>
#include <hip/hip_bf16.h>
#include <stdint.h>

#define DI __device__ __forceinline__

typedef __attribute__((ext_vector_type(8))) short short8;
typedef __attribute__((ext_vector_type(4))) short short4v;
typedef __attribute__((ext_vector_type(4))) float f32x4;

static constexpr int TT = 4096;   // seq len
static constexpr int CC = 1024;   // n_embed
static constexpr int HH = 64;     // head size

DI short f2b(float x) {
  __hip_bfloat16 h = __float2bfloat16(x);
  return __builtin_bit_cast(short, h);
}

DI f32x4 MFMA(short8 a, short8 b, f32x4 c) {
  return __builtin_amdgcn_mfma_f32_16x16x32_bf16(a, b, c, 0, 0, 0);
}

// ---------------------------------------------------------------------------
// Kernel 0: transpose weights W[k][n] f32 -> Wt[mat][n][k] bf16  (3*64*1024)
// ---------------------------------------------------------------------------
__global__ __launch_bounds__(256) void prep_wt(const float* __restrict__ Wq,
                                               const float* __restrict__ Wk,
                                               const float* __restrict__ Wv,
                                               short* __restrict__ Wt) {
  int o = blockIdx.x * 256 + threadIdx.x;       // < 196608
  int mat = o >> 16;
  int rem = o & 65535;
  int n = rem >> 10;
  int k = rem & 1023;
  const float* W = (mat == 0) ? Wq : ((mat == 1) ? Wk : Wv);
  Wt[o] = f2b(W[k * HH + n]);
}

// ---------------------------------------------------------------------------
// Kernel 1: fused QKV projection, barrier-free K-split (validated R2/R3).
// ---------------------------------------------------------------------------
__global__ __launch_bounds__(256, 2) void qkv_gemm(const float* __restrict__ x,
                                                   const short* __restrict__ Wt,
                                                   const float* __restrict__ bq,
                                                   const float* __restrict__ bk,
                                                   const float* __restrict__ bv,
                                                   short* __restrict__ qbuf,
                                                   short* __restrict__ kbuf,
                                                   short* __restrict__ vT) {
  __shared__ float lds_acc[2][32 * 196];

  const int tid = threadIdx.x;
  const int w = tid >> 6, lane = tid & 63;
  const int c = lane & 15, g = lane >> 4;
  const int m0 = blockIdx.x * 32;
  const int kb0 = w * 256;

  f32x4 acc[2][12] = {};

#pragma unroll
  for (int s8 = 0; s8 < 8; ++s8) {
    const int k0 = kb0 + s8 * 32;
    short8 afr[2];
#pragma unroll
    for (int mf = 0; mf < 2; ++mf) {
      const float* ap = x + (size_t)(m0 + 16 * mf + c) * CC + k0 + 8 * g;
      float4 a0 = ((const float4*)ap)[0];
      float4 a1 = ((const float4*)ap)[1];
      short8 p;
      p[0] = f2b(a0.x); p[1] = f2b(a0.y); p[2] = f2b(a0.z); p[3] = f2b(a0.w);
      p[4] = f2b(a1.x); p[5] = f2b(a1.y); p[6] = f2b(a1.z); p[7] = f2b(a1.w);
      afr[mf] = p;
    }
#pragma unroll
    for (int nf = 0; nf < 12; ++nf) {
      const int mat = nf >> 2;
      const int nn = (nf & 3) * 16 + c;
      short8 bfr = *(const short8*)(Wt + mat * 65536 + nn * CC + k0 + 8 * g);
      acc[0][nf] = MFMA(afr[0], bfr, acc[0][nf]);
      acc[1][nf] = MFMA(afr[1], bfr, acc[1][nf]);
    }
  }

  float* bufA = lds_acc[0];
  float* bufB = lds_acc[1];
  if (w >= 2) {
    float* buf = (w == 2) ? bufA : bufB;
#pragma unroll
    for (int mf = 0; mf < 2; ++mf)
#pragma unroll
      for (int nf = 0; nf < 12; ++nf)
#pragma unroll
        for (int r = 0; r < 4; ++r)
          buf[(16 * mf + 4 * g + r) * 196 + 16 * nf + c] = acc[mf][nf][r];
  }
  __syncthreads();
  if (w < 2) {
    float* buf = (w == 0) ? bufA : bufB;
#pragma unroll
    for (int mf = 0; mf < 2; ++mf)
#pragma unroll
      for (int nf = 0; nf < 12; ++nf)
#pragma unroll
        for (int r = 0; r < 4; ++r)
          buf[(16 * mf + 4 * g + r) * 196 + 16 * nf + c] += acc[mf][nf][r];
  }
  __syncthreads();

  const float QSCALE = 0.125f * 1.44269504088896340736f;  // 1/sqrt(64)*log2(e)
  const int bb = m0 >> 12;
  const int t0 = m0 & 4095;
  if (w < 3) {
    const int n = lane;
    const int cg = w * 64 + n;
    const float* bp = (w == 0) ? bq : ((w == 1) ? bk : bv);
    const float bias = bp[n];
    const float scale = (w == 0) ? QSCALE : 1.0f;
    if (w < 2) {
      short* op = (w == 0) ? qbuf : kbuf;
#pragma unroll
      for (int row = 0; row < 32; ++row) {
        float v = bufA[row * 196 + cg] + bufB[row * 196 + cg];
        op[(size_t)(m0 + row) * HH + n] = f2b((v + bias) * scale);
      }
    } else {
#pragma unroll
      for (int r4 = 0; r4 < 8; ++r4) {
        short4v pv;
#pragma unroll
        for (int j = 0; j < 4; ++j) {
          int row = 4 * r4 + j;
          float v = bufA[row * 196 + cg] + bufB[row * 196 + cg];
          pv[j] = f2b(v + bias);
        }
        *(short4v*)(vT + (size_t)(bb * HH + n) * TT + t0 + 4 * r4) = pv;
      }
    }
  }
}

// ---------------------------------------------------------------------------
// Kernel 2: causal flash attention, 4-way split-KV (verified R3 math, no
// pins/prefetch -> no spills at the (256,4) cap). Block = one 16-row q-job,
// 4 waves = 4 KV quarters; 1024 blocks = 4 blocks/CU.
// Serpentine job map: a CU's 4 co-resident blocks get work-ranks
// {c, 63-c, 64+c, 127-c} -> per-CU tile-sum constant. Batch pinned per
// XCD-pair for K/V L2 locality.
// ---------------------------------------------------------------------------
__global__ __launch_bounds__(256, 4) void attn(const short* __restrict__ qbuf,
                                               const short* __restrict__ kbuf,
                                               const short* __restrict__ vT,
                                               float* __restrict__ out) {
  __shared__ short lds_p[4 * 16 * 72];      // per-wave P scratch
  __shared__ float lds_o[3 * 16 * 66];      // merge O from waves 1..3
  __shared__ float lds_ml[3 * 2 * 16];      // merge m,l

  const int id = blockIdx.x;                 // 0..1023
  const int xcd = id & 7;
  const int bb = xcd >> 1;                   // batch on fixed XCD pair
  const int s = id >> 3;                     // 0..127
  const int round = s >> 5, cc = s & 31;     // 4 rounds x 32 slots
  const int jhalf = (round & 1) ? (round * 32 + 31 - cc) : (round * 32 + cc);
  const int jidx = jhalf * 2 + (xcd & 1);    // 0..255, serpentine by round
  const int jj = 255 - jidx;                 // heavy jobs first
  const int tid = threadIdx.x;
  const int w = tid >> 6, lane = tid & 63;
  const int c = lane & 15, g = lane >> 4;

  const int q0 = jj * 16;
  const int nT = (jj >> 2) + 1;
  const int tlo = (w * nT) >> 2;
  const int thi = ((w + 1) * nT) >> 2;

  const short* qrow = qbuf + (size_t)(bb * TT + q0 + c) * HH;
  const short8 qfr0 = *(const short8*)(qrow + g * 8);
  const short8 qfr1 = *(const short8*)(qrow + 32 + g * 8);

  const short* kbase = kbuf + (size_t)bb * TT * HH;
  const short* vbase = vT + (size_t)bb * HH * TT;

  f32x4 acc[4] = {};
  float mreg[4], lreg[4];
#pragma unroll
  for (int r = 0; r < 4; ++r) { mreg[r] = -INFINITY; lreg[r] = 0.f; }

  short* pw = lds_p + w * 1152;
  const char* pb = (const char*)pw;

  for (int t = tlo; t < thi; ++t) {
    const int kv0 = t * 64;
    // ---- K and V fragments direct from global (L2-hot)
    short8 kf[4][2], vf[4][2];
#pragma unroll
    for (int nf = 0; nf < 4; ++nf)
#pragma unroll
      for (int ks = 0; ks < 2; ++ks)
        kf[nf][ks] = *(const short8*)(kbase + (size_t)(kv0 + 16 * nf + c) * HH +
                                      ks * 32 + g * 8);
#pragma unroll
    for (int hf = 0; hf < 4; ++hf)
#pragma unroll
      for (int ks = 0; ks < 2; ++ks)
        vf[hf][ks] = *(const short8*)(vbase + (size_t)(16 * hf + c) * TT + kv0 +
                                      ks * 32 + g * 8);

    // ---- S^ = Q K^T (exp2 domain; scale folded into q at projection)
    f32x4 sc[4] = {};
#pragma unroll
    for (int nf = 0; nf < 4; ++nf) {
      sc[nf] = MFMA(qfr0, kf[nf][0], sc[nf]);
      sc[nf] = MFMA(qfr1, kf[nf][1], sc[nf]);
    }

    // ---- causal mask (diagonal tile only)
    if (t == nT - 1) {
#pragma unroll
      for (int nf = 0; nf < 4; ++nf)
#pragma unroll
        for (int r = 0; r < 4; ++r)
          if (kv0 + 16 * nf + c > q0 + 4 * g + r) sc[nf][r] = -INFINITY;
    }

    // ---- online softmax (row = 4g+r, reduce over 16 c-lanes)
    float mn[4], al[4], rs[4];
#pragma unroll
    for (int r = 0; r < 4; ++r) {
      float v = fmaxf(fmaxf(sc[0][r], sc[1][r]), fmaxf(sc[2][r], sc[3][r]));
      v = fmaxf(v, __shfl_xor(v, 1));
      v = fmaxf(v, __shfl_xor(v, 2));
      v = fmaxf(v, __shfl_xor(v, 4));
      v = fmaxf(v, __shfl_xor(v, 8));
      mn[r] = fmaxf(mreg[r], v);
      al[r] = exp2f(mreg[r] - mn[r]);
      rs[r] = 0.f;
    }
#pragma unroll
    for (int nf = 0; nf < 4; ++nf)
#pragma unroll
      for (int r = 0; r < 4; ++r) {
        float p = exp2f(sc[nf][r] - mn[r]);
        rs[r] += p;
        pw[(4 * g + r) * 72 + 16 * nf + c] = f2b(p);
      }
#pragma unroll
    for (int r = 0; r < 4; ++r) {
      float v = rs[r];
      v += __shfl_xor(v, 1);
      v += __shfl_xor(v, 2);
      v += __shfl_xor(v, 4);
      v += __shfl_xor(v, 8);
      lreg[r] = al[r] * lreg[r] + v;
      mreg[r] = mn[r];
    }
#pragma unroll
    for (int hf = 0; hf < 4; ++hf)
#pragma unroll
      for (int r = 0; r < 4; ++r) acc[hf][r] *= al[r];

    // ---- O += P V
#pragma unroll
    for (int ks = 0; ks < 2; ++ks) {
      short8 pa = *(const short8*)(pb + c * 144 + ks * 64 + g * 16);
#pragma unroll
      for (int hf = 0; hf < 4; ++hf)
        acc[hf] = MFMA(pa, vf[hf][ks], acc[hf]);
    }
  }

  // ---- 4-way merge: waves 1..3 dump, wave 0 combines + stores
  __syncthreads();
  if (w > 0) {
    float* od = lds_o + (w - 1) * (16 * 66);
#pragma unroll
    for (int hf = 0; hf < 4; ++hf)
#pragma unroll
      for (int r = 0; r < 4; ++r)
        od[(4 * g + r) * 66 + 16 * hf + c] = acc[hf][r];
    if (c == 0) {
      float* ml = lds_ml + (w - 1) * 32;
#pragma unroll
      for (int r = 0; r < 4; ++r) {
        ml[4 * g + r] = mreg[r];
        ml[16 + 4 * g + r] = lreg[r];
      }
    }
  }
  __syncthreads();
  if (w == 0) {
#pragma unroll
    for (int r = 0; r < 4; ++r) {
      float m = mreg[r];
      float ms[3], ls[3];
#pragma unroll
      for (int s2 = 0; s2 < 3; ++s2) {
        ms[s2] = lds_ml[s2 * 32 + 4 * g + r];
        ls[s2] = lds_ml[s2 * 32 + 16 + 4 * g + r];
        m = fmaxf(m, ms[s2]);
      }
      float a0 = exp2f(mreg[r] - m);
      float denom = a0 * lreg[r];
      float as[3];
#pragma unroll
      for (int s2 = 0; s2 < 3; ++s2) {
        as[s2] = exp2f(ms[s2] - m);
        denom += as[s2] * ls[s2];
      }
      float inv = 1.0f / denom;
      float* orow = out + (size_t)(bb * TT + q0 + 4 * g + r) * HH;
#pragma unroll
      for (int hf = 0; hf < 4; ++hf) {
        float v = a0 * acc[hf][r];
#pragma unroll
        for (int s2 = 0; s2 < 3; ++s2)
          v += as[s2] * lds_o[s2 * (16 * 66) + (4 * g + r) * 66 + 16 * hf + c];
        orow[16 * hf + c] = v * inv;
      }
    }
  }
}

// ---------------------------------------------------------------------------
extern "C" void kernel_launch(void* const* d_in, const int* in_sizes, int n_in,
                              void* d_out, int out_size, void* d_ws, size_t ws_size,
                              hipStream_t stream) {
  const float* x  = (const float*)d_in[0];
  const float* Wq = (const float*)d_in[1];
  const float* bq = (const float*)d_in[2];
  const float* Wk = (const float*)d_in[3];
  const float* bk = (const float*)d_in[4];
  const float* Wv = (const float*)d_in[5];
  const float* bv = (const float*)d_in[6];
  float* out = (float*)d_out;

  char* ws = (char*)d_ws;
  short* Wt = (short*)ws;                           // 3*64*1024 bf16 = 384 KB
  short* qb = (short*)(ws + 393216);                // 16384*64 bf16 = 2 MB
  short* kb = qb + 16384 * 64;
  short* vT = kb + 16384 * 64;                      // total ~6.7 MB

  prep_wt<<<dim3(768), dim3(256), 0, stream>>>(Wq, Wk, Wv, Wt);
  qkv_gemm<<<dim3(512), dim3(256), 0, stream>>>(x, Wt, bq, bk, bv, qb, kb, vT);
  attn<<<dim3(1024), dim3(256), 0, stream>>>(qb, kb, vT, out);
}

// Round 7
// 165.987 us; speedup vs baseline: 1.4241x; 1.1721x over previous
//
#include <hip/hip_runtime.h>
#include <hip/hip_bf16.h>
#include <stdint.h>

#define DI __device__ __forceinline__

typedef __attribute__((ext_vector_type(8))) short short8;
typedef __attribute__((ext_vector_type(4))) short short4v;
typedef __attribute__((ext_vector_type(4))) float f32x4;
typedef __attribute__((ext_vector_type(16))) float f32x16;

static constexpr int TT = 4096;   // seq len
static constexpr int CC = 1024;   // n_embed
static constexpr int HH = 64;     // head size

DI short f2b(float x) {
  __hip_bfloat16 h = __float2bfloat16(x);
  return __builtin_bit_cast(short, h);
}
DI unsigned packbf(float lo, float hi) {
  return (unsigned)(unsigned short)f2b(lo) |
         ((unsigned)(unsigned short)f2b(hi) << 16);
}

DI f32x4 MFMA(short8 a, short8 b, f32x4 c) {
  return __builtin_amdgcn_mfma_f32_16x16x32_bf16(a, b, c, 0, 0, 0);
}
DI f32x16 MFMA32(short8 a, short8 b, f32x16 c) {
  return __builtin_amdgcn_mfma_f32_32x32x16_bf16(a, b, c, 0, 0, 0);
}

// ---------------------------------------------------------------------------
// Kernel 0: transpose weights W[k][n] f32 -> Wt[mat][n][k] bf16  (3*64*1024)
// ---------------------------------------------------------------------------
__global__ __launch_bounds__(256) void prep_wt(const float* __restrict__ Wq,
                                               const float* __restrict__ Wk,
                                               const float* __restrict__ Wv,
                                               short* __restrict__ Wt) {
  int o = blockIdx.x * 256 + threadIdx.x;       // < 196608
  int mat = o >> 16;
  int rem = o & 65535;
  int n = rem >> 10;
  int k = rem & 1023;
  const float* W = (mat == 0) ? Wq : ((mat == 1) ? Wk : Wv);
  Wt[o] = f2b(W[k * HH + n]);
}

// ---------------------------------------------------------------------------
// Kernel 1: fused QKV projection, barrier-free K-split (validated R2/R6).
// ---------------------------------------------------------------------------
__global__ __launch_bounds__(256, 2) void qkv_gemm(const float* __restrict__ x,
                                                   const short* __restrict__ Wt,
                                                   const float* __restrict__ bq,
                                                   const float* __restrict__ bk,
                                                   const float* __restrict__ bv,
                                                   short* __restrict__ qbuf,
                                                   short* __restrict__ kbuf,
                                                   short* __restrict__ vT) {
  __shared__ float lds_acc[2][32 * 196];

  const int tid = threadIdx.x;
  const int w = tid >> 6, lane = tid & 63;
  const int c = lane & 15, g = lane >> 4;
  const int m0 = blockIdx.x * 32;
  const int kb0 = w * 256;

  f32x4 acc[2][12] = {};

#pragma unroll
  for (int s8 = 0; s8 < 8; ++s8) {
    const int k0 = kb0 + s8 * 32;
    short8 afr[2];
#pragma unroll
    for (int mf = 0; mf < 2; ++mf) {
      const float* ap = x + (size_t)(m0 + 16 * mf + c) * CC + k0 + 8 * g;
      float4 a0 = ((const float4*)ap)[0];
      float4 a1 = ((const float4*)ap)[1];
      short8 p;
      p[0] = f2b(a0.x); p[1] = f2b(a0.y); p[2] = f2b(a0.z); p[3] = f2b(a0.w);
      p[4] = f2b(a1.x); p[5] = f2b(a1.y); p[6] = f2b(a1.z); p[7] = f2b(a1.w);
      afr[mf] = p;
    }
#pragma unroll
    for (int nf = 0; nf < 12; ++nf) {
      const int mat = nf >> 2;
      const int nn = (nf & 3) * 16 + c;
      short8 bfr = *(const short8*)(Wt + mat * 65536 + nn * CC + k0 + 8 * g);
      acc[0][nf] = MFMA(afr[0], bfr, acc[0][nf]);
      acc[1][nf] = MFMA(afr[1], bfr, acc[1][nf]);
    }
  }

  float* bufA = lds_acc[0];
  float* bufB = lds_acc[1];
  if (w >= 2) {
    float* buf = (w == 2) ? bufA : bufB;
#pragma unroll
    for (int mf = 0; mf < 2; ++mf)
#pragma unroll
      for (int nf = 0; nf < 12; ++nf)
#pragma unroll
        for (int r = 0; r < 4; ++r)
          buf[(16 * mf + 4 * g + r) * 196 + 16 * nf + c] = acc[mf][nf][r];
  }
  __syncthreads();
  if (w < 2) {
    float* buf = (w == 0) ? bufA : bufB;
#pragma unroll
    for (int mf = 0; mf < 2; ++mf)
#pragma unroll
      for (int nf = 0; nf < 12; ++nf)
#pragma unroll
        for (int r = 0; r < 4; ++r)
          buf[(16 * mf + 4 * g + r) * 196 + 16 * nf + c] += acc[mf][nf][r];
  }
  __syncthreads();

  const float QSCALE = 0.125f * 1.44269504088896340736f;  // 1/sqrt(64)*log2(e)
  const int bb = m0 >> 12;
  const int t0 = m0 & 4095;
  if (w < 3) {
    const int n = lane;
    const int cg = w * 64 + n;
    const float* bp = (w == 0) ? bq : ((w == 1) ? bk : bv);
    const float bias = bp[n];
    const float scale = (w == 0) ? QSCALE : 1.0f;
    if (w < 2) {
      short* op = (w == 0) ? qbuf : kbuf;
#pragma unroll
      for (int row = 0; row < 32; ++row) {
        float v = bufA[row * 196 + cg] + bufB[row * 196 + cg];
        op[(size_t)(m0 + row) * HH + n] = f2b((v + bias) * scale);
      }
    } else {
#pragma unroll
      for (int r4 = 0; r4 < 8; ++r4) {
        short4v pv;
#pragma unroll
        for (int j = 0; j < 4; ++j) {
          int row = 4 * r4 + j;
          float v = bufA[row * 196 + cg] + bufB[row * 196 + cg];
          pv[j] = f2b(v + bias);
        }
        *(short4v*)(vT + (size_t)(bb * HH + n) * TT + t0 + 4 * r4) = pv;
      }
    }
  }
}

// ---------------------------------------------------------------------------
// Kernel 2: causal flash attention, swapped-operand 32x32 MFMA core.
// Block = one 32-row q-job, 4 waves = 4 KV quarters (tiles of 32 kt).
// S^T = mfma32(K, Q): lane owns q-row lane&31, 16 scores in regs.
// Softmax per-lane + __shfl_xor(.,32) cross-half (2 shfls/tile, no asm).
// P^T staged via wave-private LDS: 4x ds_write_b64 + 2x ds_read_b128/tile.
// O^T += mfma32(V^T, P). 4-way LDS merge. 512 blocks, balanced-pair map.
// ---------------------------------------------------------------------------
__global__ __launch_bounds__(256, 2) void attn(const short* __restrict__ qbuf,
                                               const short* __restrict__ kbuf,
                                               const short* __restrict__ vT,
                                               float* __restrict__ out) {
  __shared__ short lds_pt[4 * 32 * 40];     // per-wave P^T [q][kt], stride 40
  __shared__ float4 lds_od[3 * 8 * 64];     // merge O^T from waves 1..3
  __shared__ float lds_ml[3 * 128];         // merge m,l

  const int id = blockIdx.x;                 // 0..511
  const int xcd = id & 7, slot = id >> 3;    // CU c hosts slots c and c+32
  const int rix = (slot < 32) ? slot : (95 - slot);  // pair {s, 63-s}
  const int rank = rix * 8 + xcd;            // desc-sorted work rank
  const int jj = 127 - (rank >> 2);          // q-tile (32 rows)
  const int bb = rank & 3;                   // batch

  const int tid = threadIdx.x;
  const int w = tid >> 6, lane = tid & 63;
  const int ql = lane & 31;
  const int hi = lane >> 5;
  const int q0 = jj * 32;
  const int nT = jj + 1;                     // causal 32-kt tiles
  const int tlo = (w * nT) >> 2, thi = ((w + 1) * nT) >> 2;

  // Q fragments (B-operand): B[h = 16*kk + 8*hi + j][col = ql]
  const short* qr = qbuf + (size_t)(bb * TT + q0 + ql) * HH + 8 * hi;
  const short8 qf0 = *(const short8*)(qr);
  const short8 qf1 = *(const short8*)(qr + 16);
  const short8 qf2 = *(const short8*)(qr + 32);
  const short8 qf3 = *(const short8*)(qr + 48);

  const short* kB = kbuf + (size_t)bb * TT * HH;
  const short* vB = vT + (size_t)bb * HH * TT;

  f32x16 accO0 = {0,0,0,0,0,0,0,0,0,0,0,0,0,0,0,0};
  f32x16 accO1 = {0,0,0,0,0,0,0,0,0,0,0,0,0,0,0,0};
  float m = -INFINITY, l = 0.f;

  short* ptw = lds_pt + w * 1280;            // this wave's P^T (32 x 40)

  for (int t = tlo; t < thi; ++t) {
    const int kv0 = t * 32;
    // ---- K fragments (A-operand): A[row = kt_local = ql][k = h = 8*hi + j]
    const short* krow = kB + (size_t)(kv0 + ql) * HH + 8 * hi;
    short8 kf0 = *(const short8*)(krow);
    short8 kf1 = *(const short8*)(krow + 16);
    short8 kf2 = *(const short8*)(krow + 32);
    short8 kf3 = *(const short8*)(krow + 48);
    // ---- V fragments (A-operand): A[row = h' = ql][k = kt = 16*kk + 8*hi + j]
    const short* vrow = vB + (size_t)ql * TT + kv0 + 8 * hi;
    short8 vf00 = *(const short8*)(vrow);            // h'=ql      kk=0
    short8 vf01 = *(const short8*)(vrow + 16);       // h'=ql      kk=1
    short8 vf10 = *(const short8*)(vrow + 32 * TT);  // h'=32+ql   kk=0
    short8 vf11 = *(const short8*)(vrow + 32 * TT + 16);

    // ---- S^T[kt][q] (exp2 domain; scale folded into q)
    f32x16 sc = {0,0,0,0,0,0,0,0,0,0,0,0,0,0,0,0};
    sc = MFMA32(kf0, qf0, sc);
    sc = MFMA32(kf1, qf1, sc);
    sc = MFMA32(kf2, qf2, sc);
    sc = MFMA32(kf3, qf3, sc);

    // ---- causal mask (diagonal tile): kt = kv0 + (r&3) + 8*(r>>2) + 4*hi
    if (t == nT - 1) {
#pragma unroll
      for (int r = 0; r < 16; ++r) {
        int kt = kv0 + (r & 3) + 8 * (r >> 2) + 4 * hi;
        if (kt > q0 + ql) sc[r] = -INFINITY;
      }
    }

    // ---- online softmax: lane owns one q-row; cross-half via shfl_xor(32)
    float tm = fmaxf(fmaxf(fmaxf(sc[0], sc[1]), fmaxf(sc[2], sc[3])),
                     fmaxf(fmaxf(sc[4], sc[5]), fmaxf(sc[6], sc[7])));
    float tm2 = fmaxf(fmaxf(fmaxf(sc[8], sc[9]), fmaxf(sc[10], sc[11])),
                      fmaxf(fmaxf(sc[12], sc[13]), fmaxf(sc[14], sc[15])));
    tm = fmaxf(tm, tm2);
    tm = fmaxf(tm, __shfl_xor(tm, 32));      // full 32-row max, both halves
    if (__any(tm > m + 8.0f)) {              // defer-max (THR=8, exp2 domain)
      float mn = fmaxf(m, tm);
      float al = exp2f(m - mn);
      l *= al;
#pragma unroll
      for (int r = 0; r < 16; ++r) { accO0[r] *= al; accO1[r] *= al; }
      m = mn;
    }
    float p[16];
    float rs = 0.f;
#pragma unroll
    for (int r = 0; r < 16; ++r) {
      p[r] = exp2f(sc[r] - m);
      rs += p[r];
    }
    l += rs + __shfl_xor(rs, 32);

    // ---- P^T -> LDS: rows kt_local = 8*rg + 4*hi + {0..3} from p[4rg..4rg+3]
#pragma unroll
    for (int rg = 0; rg < 4; ++rg) {
      uint2 d;
      d.x = packbf(p[4 * rg], p[4 * rg + 1]);
      d.y = packbf(p[4 * rg + 2], p[4 * rg + 3]);
      *(uint2*)(ptw + ql * 40 + 8 * rg + 4 * hi) = d;
    }
    // ---- P fragments (B-operand): B[k = 8*hi + j][col = ql]
    short8 pf0 = *(const short8*)(ptw + ql * 40 + 8 * hi);        // kt [0,16)
    short8 pf1 = *(const short8*)(ptw + ql * 40 + 16 + 8 * hi);   // kt [16,32)

    // ---- O^T += V^T P
    accO0 = MFMA32(vf00, pf0, accO0);
    accO0 = MFMA32(vf01, pf1, accO0);
    accO1 = MFMA32(vf10, pf0, accO1);
    accO1 = MFMA32(vf11, pf1, accO1);
  }

  // ---- 4-way merge: waves 1..3 dump (O^T, m, l); wave 0 combines + stores
  __syncthreads();
  if (w > 0) {
#pragma unroll
    for (int rq = 0; rq < 4; ++rq) {
      float4 t0, t1;
      t0.x = accO0[4 * rq]; t0.y = accO0[4 * rq + 1];
      t0.z = accO0[4 * rq + 2]; t0.w = accO0[4 * rq + 3];
      t1.x = accO1[4 * rq]; t1.y = accO1[4 * rq + 1];
      t1.z = accO1[4 * rq + 2]; t1.w = accO1[4 * rq + 3];
      lds_od[((w - 1) * 8 + rq) * 64 + lane] = t0;
      lds_od[((w - 1) * 8 + 4 + rq) * 64 + lane] = t1;
    }
    lds_ml[(w - 1) * 128 + lane] = m;
    lds_ml[(w - 1) * 128 + 64 + lane] = l;
  }
  __syncthreads();
  if (w == 0) {
    float m1 = lds_ml[lane],       l1 = lds_ml[64 + lane];
    float m2 = lds_ml[128 + lane], l2 = lds_ml[192 + lane];
    float m3 = lds_ml[256 + lane], l3 = lds_ml[320 + lane];
    float ms = fmaxf(fmaxf(m, m1), fmaxf(m2, m3));
    float c0 = exp2f(m - ms), c1 = exp2f(m1 - ms);
    float c2 = exp2f(m2 - ms), c3 = exp2f(m3 - ms);
    float inv = 1.0f / (c0 * l + c1 * l1 + c2 * l2 + c3 * l3);
    float* orow = out + (size_t)(bb * TT + q0 + ql) * HH;
#pragma unroll
    for (int rq = 0; rq < 8; ++rq) {
      float4 v1 = lds_od[(0 * 8 + rq) * 64 + lane];
      float4 v2 = lds_od[(1 * 8 + rq) * 64 + lane];
      float4 v3 = lds_od[(2 * 8 + rq) * 64 + lane];
      float o0, o1, o2, o3;
      if (rq < 4) {
        o0 = accO0[4 * (rq & 3)];     o1 = accO0[4 * (rq & 3) + 1];
        o2 = accO0[4 * (rq & 3) + 2]; o3 = accO0[4 * (rq & 3) + 3];
      } else {
        o0 = accO1[4 * (rq & 3)];     o1 = accO1[4 * (rq & 3) + 1];
        o2 = accO1[4 * (rq & 3) + 2]; o3 = accO1[4 * (rq & 3) + 3];
      }
      float4 res;
      res.x = (c0 * o0 + c1 * v1.x + c2 * v2.x + c3 * v3.x) * inv;
      res.y = (c0 * o1 + c1 * v1.y + c2 * v2.y + c3 * v3.y) * inv;
      res.z = (c0 * o2 + c1 * v1.z + c2 * v2.z + c3 * v3.z) * inv;
      res.w = (c0 * o3 + c1 * v1.w + c2 * v2.w + c3 * v3.w) * inv;
      const int ht = rq >> 2, r2 = rq & 3;
      *(float4*)(orow + 32 * ht + 8 * r2 + 4 * hi) = res;
    }
  }
}

// ---------------------------------------------------------------------------
extern "C" void kernel_launch(void* const* d_in, const int* in_sizes, int n_in,
                              void* d_out, int out_size, void* d_ws, size_t ws_size,
                              hipStream_t stream) {
  const float* x  = (const float*)d_in[0];
  const float* Wq = (const float*)d_in[1];
  const float* bq = (const float*)d_in[2];
  const float* Wk = (const float*)d_in[3];
  const float* bk = (const float*)d_in[4];
  const float* Wv = (const float*)d_in[5];
  const float* bv = (const float*)d_in[6];
  float* out = (float*)d_out;

  char* ws = (char*)d_ws;
  short* Wt = (short*)ws;                           // 3*64*1024 bf16 = 384 KB
  short* qb = (short*)(ws + 393216);                // 16384*64 bf16 = 2 MB
  short* kb = qb + 16384 * 64;
  short* vT = kb + 16384 * 64;                      // total ~6.7 MB

  prep_wt<<<dim3(768), dim3(256), 0, stream>>>(Wq, Wk, Wv, Wt);
  qkv_gemm<<<dim3(512), dim3(256), 0, stream>>>(x, Wt, bq, bk, bv, qb, kb, vT);
  attn<<<dim3(512), dim3(256), 0, stream>>>(qb, kb, vT, out);
}

// Round 8
// 150.536 us; speedup vs baseline: 1.5703x; 1.1026x over previous
//
#include <hip/hip_runtime.h>
#include <hip/hip_bf16.h>
#include <stdint.h>

#define DI __device__ __forceinline__

typedef __attribute__((ext_vector_type(8))) short short8;
typedef __attribute__((ext_vector_type(4))) short short4v;
typedef __attribute__((ext_vector_type(4))) float f32x4;
typedef __attribute__((ext_vector_type(16))) float f32x16;

static constexpr int TT = 4096;   // seq len
static constexpr int CC = 1024;   // n_embed
static constexpr int HH = 64;     // head size

DI short f2b(float x) {
  __hip_bfloat16 h = __float2bfloat16(x);
  return __builtin_bit_cast(short, h);
}
DI unsigned packbf(float lo, float hi) {
  return (unsigned)(unsigned short)f2b(lo) |
         ((unsigned)(unsigned short)f2b(hi) << 16);
}

DI f32x4 MFMA(short8 a, short8 b, f32x4 c) {
  return __builtin_amdgcn_mfma_f32_16x16x32_bf16(a, b, c, 0, 0, 0);
}
DI f32x16 MFMA32(short8 a, short8 b, f32x16 c) {
  return __builtin_amdgcn_mfma_f32_32x32x16_bf16(a, b, c, 0, 0, 0);
}

DI void gload_lds16(const void* g, void* l) {
  __builtin_amdgcn_global_load_lds(
      (__attribute__((address_space(1))) void*)(void*)(uintptr_t)g,
      (__attribute__((address_space(3))) void*)(void*)(uintptr_t)l, 16, 0, 0);
}

// ---------------------------------------------------------------------------
// Kernel 0: transpose weights W[k][n] f32 -> Wt[mat][n][k] bf16  (3*64*1024)
// ---------------------------------------------------------------------------
__global__ __launch_bounds__(256) void prep_wt(const float* __restrict__ Wq,
                                               const float* __restrict__ Wk,
                                               const float* __restrict__ Wv,
                                               short* __restrict__ Wt) {
  int o = blockIdx.x * 256 + threadIdx.x;       // < 196608
  int mat = o >> 16;
  int rem = o & 65535;
  int n = rem >> 10;
  int k = rem & 1023;
  const float* W = (mat == 0) ? Wq : ((mat == 1) ? Wk : Wv);
  Wt[o] = f2b(W[k * HH + n]);
}

// ---------------------------------------------------------------------------
// Kernel 1: fused QKV projection — 2-phase double-buffered LDS GEMM.
// 256 blocks x 512 threads. Block = 64 rows x 192 cols, BK=64, 16 K-steps.
// A (x, f32): T14 async-split reg-staging (issue early, cvt+ds_write late),
//   xor-swizzled rows. B (Wt, bf16): global_load_lds 16B, source-swizzled,
//   linear LDS dest (rule 21). Wave (wr,wc) owns 32 rows x 48 cols.
// One barrier per K-step; epilogue straight from accumulators.
// ---------------------------------------------------------------------------
__global__ __launch_bounds__(512, 2) void qkv_gemm(const float* __restrict__ x,
                                                   const short* __restrict__ Wt,
                                                   const float* __restrict__ bq,
                                                   const float* __restrict__ bk,
                                                   const float* __restrict__ bv,
                                                   short* __restrict__ qbuf,
                                                   short* __restrict__ kbuf,
                                                   short* __restrict__ vT) {
  __shared__ short lds_a[2 * 64 * 64];     // [buf][row][k] 128B rows, swizzled
  __shared__ short lds_b[2 * 192 * 64];    // [buf][n][k] 128B rows, swizzled

  const int tid = threadIdx.x;
  const int w = tid >> 6, lane = tid & 63;
  const int wr = w >> 2, wc = w & 3;
  const int c = lane & 15, g = lane >> 4;
  const int m0 = blockIdx.x * 64;
  const int ar = tid >> 3, as = tid & 7;   // A-stage: row, k-segment
  const int sw = (c & 7) << 4;

  f32x4 acc[2][3] = {};   // [mf][nf]

  // ---- prologue: stage K-step 0 into buffer 0
  {
    const float* ap = x + (size_t)(m0 + ar) * CC + 8 * as;
    float4 a0 = ((const float4*)ap)[0];
    float4 a1 = ((const float4*)ap)[1];
    uint2 d0, d1;
    d0.x = packbf(a0.x, a0.y); d0.y = packbf(a0.z, a0.w);
    d1.x = packbf(a1.x, a1.y); d1.y = packbf(a1.z, a1.w);
    uint4 pk = {d0.x, d0.y, d1.x, d1.y};
    *(uint4*)((char*)lds_a + ar * 128 + ((16 * as) ^ ((ar & 7) << 4))) = pk;
#pragma unroll
    for (int ch = 0; ch < 3; ++ch) {
      int n = ch * 64 + w * 8 + (lane >> 3);
      int q = lane & 7;
      gload_lds16(Wt + n * CC + 8 * (q ^ (n & 7)),
                  lds_b + (ch * 512 + w * 64) * 8);
    }
  }
  __syncthreads();

  for (int t = 0; t < 16; ++t) {
    const int cur = t & 1, nxt = cur ^ 1;
    const short* Ab = lds_a + cur * 4096;
    const short* Bb = lds_b + cur * 12288;

    // ---- (1) issue next A-tile global loads (consumed after compute, T14)
    float4 xa0, xa1;
    if (t + 1 < 16) {
      const float* ap = x + (size_t)(m0 + ar) * CC + (t + 1) * 64 + 8 * as;
      xa0 = ((const float4*)ap)[0];
      xa1 = ((const float4*)ap)[1];
      // ---- (2) issue next B-tile global_load_lds (drained by the barrier)
#pragma unroll
      for (int ch = 0; ch < 3; ++ch) {
        int n = ch * 64 + w * 8 + (lane >> 3);
        int q = lane & 7;
        gload_lds16(Wt + n * CC + (t + 1) * 64 + 8 * (q ^ (n & 7)),
                    lds_b + nxt * 12288 + (ch * 512 + w * 64) * 8);
      }
    }

    // ---- (3) fragments from LDS + MFMA
    short8 afr[2][2], bfr[3][2];
#pragma unroll
    for (int mf = 0; mf < 2; ++mf)
#pragma unroll
      for (int ks = 0; ks < 2; ++ks) {
        int row = 32 * wr + 16 * mf + c;
        afr[mf][ks] = *(const short8*)((const char*)Ab + row * 128 +
                                       ((ks * 64 + g * 16) ^ sw));
      }
#pragma unroll
    for (int nf = 0; nf < 3; ++nf)
#pragma unroll
      for (int ks = 0; ks < 2; ++ks) {
        int n = 48 * wc + 16 * nf + c;
        bfr[nf][ks] = *(const short8*)((const char*)Bb + n * 128 +
                                       ((ks * 64 + g * 16) ^ sw));
      }
#pragma unroll
    for (int ks = 0; ks < 2; ++ks)
#pragma unroll
      for (int mf = 0; mf < 2; ++mf)
#pragma unroll
        for (int nf = 0; nf < 3; ++nf)
          acc[mf][nf] = MFMA(afr[mf][ks], bfr[nf][ks], acc[mf][nf]);

    // ---- (4) convert + write next A-tile to LDS (loads landed under compute)
    if (t + 1 < 16) {
      uint2 d0, d1;
      d0.x = packbf(xa0.x, xa0.y); d0.y = packbf(xa0.z, xa0.w);
      d1.x = packbf(xa1.x, xa1.y); d1.y = packbf(xa1.z, xa1.w);
      uint4 pk = {d0.x, d0.y, d1.x, d1.y};
      *(uint4*)((char*)lds_a + nxt * 8192 + ar * 128 +
                ((16 * as) ^ ((ar & 7) << 4))) = pk;
    }
    // ---- (5) barrier (drains gload_lds + ds_writes)
    __syncthreads();
  }

  // ---- epilogue: +bias, scale (q), bf16 stores; V written transposed
  const float QSCALE = 0.125f * 1.44269504088896340736f;  // 1/sqrt(64)*log2(e)
  const int bb = m0 >> 12;
  const int t0 = m0 & 4095;
#pragma unroll
  for (int nf = 0; nf < 3; ++nf) {
    const int col0 = 48 * wc + 16 * nf;
    const int mat = col0 >> 6;
    const int n = (col0 & 63) + c;
    const float* bp = (mat == 0) ? bq : ((mat == 1) ? bk : bv);
    const float bias = bp[n];
    if (mat < 2) {
      short* op = (mat == 0) ? qbuf : kbuf;
      const float scale = (mat == 0) ? QSCALE : 1.0f;
#pragma unroll
      for (int mf = 0; mf < 2; ++mf)
#pragma unroll
        for (int r = 0; r < 4; ++r) {
          int mrow = m0 + 32 * wr + 16 * mf + 4 * g + r;
          op[(size_t)mrow * HH + n] = f2b((acc[mf][nf][r] + bias) * scale);
        }
    } else {
#pragma unroll
      for (int mf = 0; mf < 2; ++mf) {
        short4v pv;
#pragma unroll
        for (int r = 0; r < 4; ++r) pv[r] = f2b(acc[mf][nf][r] + bias);
        *(short4v*)(vT + (size_t)(bb * HH + n) * TT + t0 + 32 * wr + 16 * mf +
                    4 * g) = pv;
      }
    }
  }
}

// ---------------------------------------------------------------------------
// Kernel 2: causal flash attention, swapped-operand 32x32 MFMA core
// (verified R7). Block = one 32-row q-job, 4 waves = 4 KV quarters.
// ---------------------------------------------------------------------------
__global__ __launch_bounds__(256, 2) void attn(const short* __restrict__ qbuf,
                                               const short* __restrict__ kbuf,
                                               const short* __restrict__ vT,
                                               float* __restrict__ out) {
  __shared__ short lds_pt[4 * 32 * 40];     // per-wave P^T [q][kt], stride 40
  __shared__ float4 lds_od[3 * 8 * 64];     // merge O^T from waves 1..3
  __shared__ float lds_ml[3 * 128];         // merge m,l

  const int id = blockIdx.x;                 // 0..511
  const int xcd = id & 7, slot = id >> 3;    // CU c hosts slots c and c+32
  const int rix = (slot < 32) ? slot : (95 - slot);  // pair {s, 63-s}
  const int rank = rix * 8 + xcd;            // desc-sorted work rank
  const int jj = 127 - (rank >> 2);          // q-tile (32 rows)
  const int bb = rank & 3;                   // batch

  const int tid = threadIdx.x;
  const int w = tid >> 6, lane = tid & 63;
  const int ql = lane & 31;
  const int hi = lane >> 5;
  const int q0 = jj * 32;
  const int nT = jj + 1;                     // causal 32-kt tiles
  const int tlo = (w * nT) >> 2, thi = ((w + 1) * nT) >> 2;

  // Q fragments (B-operand): B[h = 16*kk + 8*hi + j][col = ql]
  const short* qr = qbuf + (size_t)(bb * TT + q0 + ql) * HH + 8 * hi;
  const short8 qf0 = *(const short8*)(qr);
  const short8 qf1 = *(const short8*)(qr + 16);
  const short8 qf2 = *(const short8*)(qr + 32);
  const short8 qf3 = *(const short8*)(qr + 48);

  const short* kB = kbuf + (size_t)bb * TT * HH;
  const short* vB = vT + (size_t)bb * HH * TT;

  f32x16 accO0 = {0,0,0,0,0,0,0,0,0,0,0,0,0,0,0,0};
  f32x16 accO1 = {0,0,0,0,0,0,0,0,0,0,0,0,0,0,0,0};
  float m = -INFINITY, l = 0.f;

  short* ptw = lds_pt + w * 1280;            // this wave's P^T (32 x 40)

  for (int t = tlo; t < thi; ++t) {
    const int kv0 = t * 32;
    // ---- K fragments (A-operand): A[row = kt_local = ql][k = h = 8*hi + j]
    const short* krow = kB + (size_t)(kv0 + ql) * HH + 8 * hi;
    short8 kf0 = *(const short8*)(krow);
    short8 kf1 = *(const short8*)(krow + 16);
    short8 kf2 = *(const short8*)(krow + 32);
    short8 kf3 = *(const short8*)(krow + 48);
    // ---- V fragments (A-operand): A[row = h' = ql][k = kt = 16*kk + 8*hi + j]
    const short* vrow = vB + (size_t)ql * TT + kv0 + 8 * hi;
    short8 vf00 = *(const short8*)(vrow);            // h'=ql      kk=0
    short8 vf01 = *(const short8*)(vrow + 16);       // h'=ql      kk=1
    short8 vf10 = *(const short8*)(vrow + 32 * TT);  // h'=32+ql   kk=0
    short8 vf11 = *(const short8*)(vrow + 32 * TT + 16);

    // ---- S^T[kt][q] (exp2 domain; scale folded into q)
    f32x16 sc = {0,0,0,0,0,0,0,0,0,0,0,0,0,0,0,0};
    sc = MFMA32(kf0, qf0, sc);
    sc = MFMA32(kf1, qf1, sc);
    sc = MFMA32(kf2, qf2, sc);
    sc = MFMA32(kf3, qf3, sc);

    // ---- causal mask (diagonal tile): kt = kv0 + (r&3) + 8*(r>>2) + 4*hi
    if (t == nT - 1) {
#pragma unroll
      for (int r = 0; r < 16; ++r) {
        int kt = kv0 + (r & 3) + 8 * (r >> 2) + 4 * hi;
        if (kt > q0 + ql) sc[r] = -INFINITY;
      }
    }

    // ---- online softmax: lane owns one q-row; cross-half via shfl_xor(32)
    float tm = fmaxf(fmaxf(fmaxf(sc[0], sc[1]), fmaxf(sc[2], sc[3])),
                     fmaxf(fmaxf(sc[4], sc[5]), fmaxf(sc[6], sc[7])));
    float tm2 = fmaxf(fmaxf(fmaxf(sc[8], sc[9]), fmaxf(sc[10], sc[11])),
                      fmaxf(fmaxf(sc[12], sc[13]), fmaxf(sc[14], sc[15])));
    tm = fmaxf(tm, tm2);
    tm = fmaxf(tm, __shfl_xor(tm, 32));      // full 32-row max, both halves
    if (__any(tm > m + 8.0f)) {              // defer-max (THR=8, exp2 domain)
      float mn = fmaxf(m, tm);
      float al = exp2f(m - mn);
      l *= al;
#pragma unroll
      for (int r = 0; r < 16; ++r) { accO0[r] *= al; accO1[r] *= al; }
      m = mn;
    }
    float p[16];
    float rs = 0.f;
#pragma unroll
    for (int r = 0; r < 16; ++r) {
      p[r] = exp2f(sc[r] - m);
      rs += p[r];
    }
    l += rs + __shfl_xor(rs, 32);

    // ---- P^T -> LDS: rows kt_local = 8*rg + 4*hi + {0..3} from p[4rg..4rg+3]
#pragma unroll
    for (int rg = 0; rg < 4; ++rg) {
      uint2 d;
      d.x = packbf(p[4 * rg], p[4 * rg + 1]);
      d.y = packbf(p[4 * rg + 2], p[4 * rg + 3]);
      *(uint2*)(ptw + ql * 40 + 8 * rg + 4 * hi) = d;
    }
    // ---- P fragments (B-operand): B[k = 8*hi + j][col = ql]
    short8 pf0 = *(const short8*)(ptw + ql * 40 + 8 * hi);        // kt [0,16)
    short8 pf1 = *(const short8*)(ptw + ql * 40 + 16 + 8 * hi);   // kt [16,32)

    // ---- O^T += V^T P
    accO0 = MFMA32(vf00, pf0, accO0);
    accO0 = MFMA32(vf01, pf1, accO0);
    accO1 = MFMA32(vf10, pf0, accO1);
    accO1 = MFMA32(vf11, pf1, accO1);
  }

  // ---- 4-way merge: waves 1..3 dump (O^T, m, l); wave 0 combines + stores
  __syncthreads();
  if (w > 0) {
#pragma unroll
    for (int rq = 0; rq < 4; ++rq) {
      float4 t0, t1;
      t0.x = accO0[4 * rq]; t0.y = accO0[4 * rq + 1];
      t0.z = accO0[4 * rq + 2]; t0.w = accO0[4 * rq + 3];
      t1.x = accO1[4 * rq]; t1.y = accO1[4 * rq + 1];
      t1.z = accO1[4 * rq + 2]; t1.w = accO1[4 * rq + 3];
      lds_od[((w - 1) * 8 + rq) * 64 + lane] = t0;
      lds_od[((w - 1) * 8 + 4 + rq) * 64 + lane] = t1;
    }
    lds_ml[(w - 1) * 128 + lane] = m;
    lds_ml[(w - 1) * 128 + 64 + lane] = l;
  }
  __syncthreads();
  if (w == 0) {
    float m1 = lds_ml[lane],       l1 = lds_ml[64 + lane];
    float m2 = lds_ml[128 + lane], l2 = lds_ml[192 + lane];
    float m3 = lds_ml[256 + lane], l3 = lds_ml[320 + lane];
    float ms = fmaxf(fmaxf(m, m1), fmaxf(m2, m3));
    float c0 = exp2f(m - ms), c1 = exp2f(m1 - ms);
    float c2 = exp2f(m2 - ms), c3 = exp2f(m3 - ms);
    float inv = 1.0f / (c0 * l + c1 * l1 + c2 * l2 + c3 * l3);
    float* orow = out + (size_t)(bb * TT + q0 + ql) * HH;
#pragma unroll
    for (int rq = 0; rq < 8; ++rq) {
      float4 v1 = lds_od[(0 * 8 + rq) * 64 + lane];
      float4 v2 = lds_od[(1 * 8 + rq) * 64 + lane];
      float4 v3 = lds_od[(2 * 8 + rq) * 64 + lane];
      float o0, o1, o2, o3;
      if (rq < 4) {
        o0 = accO0[4 * (rq & 3)];     o1 = accO0[4 * (rq & 3) + 1];
        o2 = accO0[4 * (rq & 3) + 2]; o3 = accO0[4 * (rq & 3) + 3];
      } else {
        o0 = accO1[4 * (rq & 3)];     o1 = accO1[4 * (rq & 3) + 1];
        o2 = accO1[4 * (rq & 3) + 2]; o3 = accO1[4 * (rq & 3) + 3];
      }
      float4 res;
      res.x = (c0 * o0 + c1 * v1.x + c2 * v2.x + c3 * v3.x) * inv;
      res.y = (c0 * o1 + c1 * v1.y + c2 * v2.y + c3 * v3.y) * inv;
      res.z = (c0 * o2 + c1 * v1.z + c2 * v2.z + c3 * v3.z) * inv;
      res.w = (c0 * o3 + c1 * v1.w + c2 * v2.w + c3 * v3.w) * inv;
      const int ht = rq >> 2, r2 = rq & 3;
      *(float4*)(orow + 32 * ht + 8 * r2 + 4 * hi) = res;
    }
  }
}

// ---------------------------------------------------------------------------
extern "C" void kernel_launch(void* const* d_in, const int* in_sizes, int n_in,
                              void* d_out, int out_size, void* d_ws, size_t ws_size,
                              hipStream_t stream) {
  const float* x  = (const float*)d_in[0];
  const float* Wq = (const float*)d_in[1];
  const float* bq = (const float*)d_in[2];
  const float* Wk = (const float*)d_in[3];
  const float* bk = (const float*)d_in[4];
  const float* Wv = (const float*)d_in[5];
  const float* bv = (const float*)d_in[6];
  float* out = (float*)d_out;

  char* ws = (char*)d_ws;
  short* Wt = (short*)ws;                           // 3*64*1024 bf16 = 384 KB
  short* qb = (short*)(ws + 393216);                // 16384*64 bf16 = 2 MB
  short* kb = qb + 16384 * 64;
  short* vT = kb + 16384 * 64;                      // total ~6.7 MB

  prep_wt<<<dim3(768), dim3(256), 0, stream>>>(Wq, Wk, Wv, Wt);
  qkv_gemm<<<dim3(256), dim3(512), 0, stream>>>(x, Wt, bq, bk, bv, qb, kb, vT);
  attn<<<dim3(512), dim3(256), 0, stream>>>(qb, kb, vT, out);
}